// Round 1
// 71.780 us; speedup vs baseline: 1.0011x; 1.0011x over previous
//
#include <hip/hip_runtime.h>
#include <math.h>

#define SZ 256
#define KNN 4
#define NUM_CHANNELS 8
#define R 7                  // main window half-width; exact iff 4th d2 < 64
#define WROWS (2 * R + 1)    // 15 main rows (clamped to image)
#define FR 16                // staged row half-range
#define FROWS (2 * FR + 1)   // 33 staged rows; unstaged rows have d2 >= 289
#define W32 10               // LDS row: [1 pad u32][8 data u32][1 pad u32]

typedef unsigned long long u64;
typedef unsigned int u32;

// v_med3_u32: median of three. Used for the branchless sorted-4 insert.
__device__ __forceinline__ u32 med3(u32 a, u32 b, u32 c) {
    u32 r;
    asm("v_med3_u32 %0, %1, %2, %3" : "=v"(r) : "v"(a), "v"(b), "v"(c));
    return r;
}

// Branchless insert into ascending sorted 4 (u32 keys), med3 form:
// 4 VALU (1 min + 3 med3), dependency depth 1 (all read OLD k's).
// Identical results to the serial min/max ladder (R8/R11 baseline):
//   new_k0 = min(key,k0); new_ki = median(key, k_{i-1}, k_i).
// key = (d2 << 16) | flat_idx; main-loop d2 <= 245 -> no overflow.
// Matches jax.lax.top_k ordering incl. lower-index tie-break (keys unique).
__device__ __forceinline__ void ins4(u32 key, u32& k0, u32& k1,
                                     u32& k2, u32& k3) {
    const u32 n1 = med3(key, k0, k1);
    const u32 n2 = med3(key, k1, k2);
    const u32 n3 = med3(key, k2, k3);
    k0 = (k0 < key) ? k0 : key;
    k1 = n1; k2 = n2; k3 = n3;
}

// u64 variant for fallbacks (d2 up to 130050 would overflow a u32 key).
__device__ __forceinline__ void ins4_64(u64 key, u64& k0, u64& k1,
                                        u64& k2, u64& k3) {
    if (key < k3) {
        u64 m;
        m = (k2 > key) ? k2 : key;  k3 = (k3 < m) ? k3 : m;
        m = (k1 > key) ? k1 : key;  k2 = (k2 < m) ? k2 : m;
        m = (k0 > key) ? k0 : key;  k1 = (k1 < m) ? k1 : m;
        k0 = (k0 < key) ? k0 : key;
    }
}

// 15-bit window extraction: one v_alignbit_b32 over two adjacent u32 words.
// alignbit = (u32)(((u64)hi << 32 | lo) >> (sh & 31)).
__device__ __forceinline__ u32 win15(u32 hi, u32 lo, u32 sh) {
    u32 r;
    asm("v_alignbit_b32 %0, %1, %2, %3" : "=v"(r) : "v"(hi), "v"(lo), "v"(sh));
    return r & 0x7FFFu;
}

// Pass 1: per-channel occupancy bitmaps via wave ballot.
// bm layout: u64[NUM_CHANNELS][SZ][4]; word j covers x in [j*64, j*64+64).
// One ballot pass over lut (256 blocks) is strictly cheaper than per-block
// ballot staging in the fill kernel (R7/R9 both regressed).
__global__ __launch_bounds__(256) void build_bitmaps(
    const int* __restrict__ lut,
    u64* __restrict__ bm)
{
    const int y = blockIdx.x;
    const int x = threadIdx.x;
    const int v = lut[y * SZ + x];
    const int lane = x & 63;
    const int w64 = x >> 6;
    #pragma unroll
    for (int c = 1; c <= NUM_CHANNELS; ++c) {
        u64 bal = __ballot(v == c);
        if (lane == 0) bm[(size_t)(c - 1) * (SZ * 4) + y * 4 + w64] = bal;
    }
}

// Pass 2: stage 33 clamped rows from the global bitmap into LDS (u32 words,
// 1-word pads); wave-uniform |dy|-ordered 15-row scan (u32 keys, med3 insert)
// with __all early break; rare LDS secondary fallback (u64 keys); ~never
// tertiary over the global bitmap.
__global__ __launch_bounds__(256) void knn_fill(
    const float* __restrict__ img,
    const u64*   __restrict__ bm,
    float*       __restrict__ out)
{
    __shared__ u32 win32[FROWS * W32];     // 1320 B padded window bitmap

    const int x   = threadIdx.x;
    const int y   = blockIdx.x;            // block-uniform -> uniform loops
    const int ch  = blockIdx.y;
    const int tid = threadIdx.x;
    const u64* bmc = bm + (size_t)ch * (SZ * 4);

    // Clamped staged-window start (33 full in-image rows).
    int y0b = y - FR;
    if (y0b < 0) y0b = 0;
    if (y0b > SZ - FROWS) y0b = SZ - FROWS;
    // Clamped main-window start (15 full in-image rows).
    int y0m = y - R;
    if (y0m < 0) y0m = 0;
    if (y0m > SZ - WROWS) y0m = SZ - WROWS;
    const int m0 = y0m - y0b;              // main rows offset in staged buf

    // Zero the 66 pad words; load the 132 contiguous u64 bitmap words and
    // scatter each as two u32s (pad indices are 0,9 mod 10 -> disjoint).
    if (tid < FROWS * 2) win32[(tid >> 1) * W32 + (tid & 1) * 9] = 0;
    if (tid < FROWS * 4) {
        const int rr = tid >> 2, j = tid & 3;
        const u64 v = bmc[(y0b + rr) * 4 + j];
        const int b = rr * W32 + 1 + j * 2;
        win32[b]     = (u32)v;
        win32[b + 1] = (u32)(v >> 32);
    }
    __syncthreads();

    const int pix = y * SZ + x;
    float* outc = out + (size_t)ch * (SZ * SZ);

    if ((win32[(y - y0b) * W32 + 1 + (x >> 5)] >> (x & 31)) & 1u) {
        outc[pix] = img[pix];
        return;
    }

    u32 k0 = ~0u, k1 = ~0u, k2 = ~0u, k3 = ~0u;

    // Padded bit position of x-R: 32-bit left pad -> bpos = x - 7 + 32.
    const int bpos = x + (32 - R);
    const int j32  = bpos >> 5;     // 0..8 (word 9 is the right pad)
    const u32 shb  = (u32)(bpos & 31);

    // Main scan, rows ordered by |dy| (block-uniform control flow).
    // The data-dependent __all break saves ~25% of row iterations and beats
    // a fully-unrolled straight scan (R10 regressed).
    for (int ady = 0; ady < WROWS; ++ady) {
        #pragma unroll
        for (int s = 0; s < 2; ++s) {
            if (s && ady == 0) continue;
            const int yy = s ? y + ady : y - ady;
            const int rr = yy - y0m;
            if (rr < 0 || rr >= WROWS) continue;     // outside clamped window
            const u32* rw = &win32[(m0 + rr) * W32 + j32];
            u32 w = win15(rw[1], rw[0], shb);        // ds_read2 + alignbit
            const int dy2  = ady * ady;
            const int rowx = yy * SZ + x;            // flat idx of (row, x)
            // Hoisted key base; u32 wraparound is exact: 0 <= rowx+dx <=
            // 65535 (candidate is in-image) and d2 <= 245.
            const u32 kb = ((u32)dy2 << 16) + (u32)rowx;
            while (w) {
                const int b = __builtin_ctz(w);
                w &= w - 1;
                const int dx  = b - R;
                const u32 key = kb + (((u32)(dx * dx)) << 16) + (u32)dx;
                ins4(key, k0, k1, k2, k3);
            }
        }
        // Remaining window rows have |dy| >= ady+1 -> candidate d2 >=
        // (ady+1)^2 > lane's k3_d2 -> key > k3 -> insert is a no-op.
        // Strict '<' preserves tie-break exactness.
        if (__all((k3 >> 16) < (u32)((ady + 1) * (ady + 1)))) break;
    }

    u64 ks[KNN];
    const u32 in_d2 = k3 >> 16;
    // Exactness: any cell outside (15 main rows ∧ |dx|<=7) has d2 >= 64.
    if (in_d2 < (u32)((R + 1) * (R + 1))) {
        ks[0] = k0; ks[1] = k1; ks[2] = k2; ks[3] = k3;  // same bit format
    } else {
        // Secondary fallback (edge pixels, ~1e-3): cap-pruned ring ctz scan
        // over the staged 33-row LDS bitmap (u32 words), u64 keys (d2 up to
        // 66049). cap = in-window 4th-best d2 (0xFFFF if <4 found) — valid
        // upper bound; a2<=cur / Rx+1 conservatism keeps tie-breaks exact.
        const u64 cap = (u64)in_d2;
        u64 q0 = ~0ull, q1 = ~0ull, q2 = ~0ull, q3 = ~0ull;
        for (int ady = 0; ady < FROWS; ++ady) {
            u64 cur = q3 >> 16;
            if (cap < cur) cur = cap;
            const u64 a2 = (u64)(ady * ady);
            if (a2 > cur) break;          // keep a2 == cur (ties)
            const u64 bound = cur - a2;
            int Rx = (bound >= 65025ull) ? (SZ - 1)
                                         : ((int)sqrtf((float)bound) + 1);
            int xs = x - Rx; if (xs < 0) xs = 0;
            int xe = x + Rx; if (xe > SZ - 1) xe = SZ - 1;
            const int jxs = xs >> 5, jxe = xe >> 5;
            const u32 mlo = (~0u) << (xs & 31);
            const u32 mhi = (~0u) >> (31 - (xe & 31));
            #pragma unroll
            for (int s = 0; s < 2; ++s) {
                if (s && ady == 0) continue;
                const int yy = s ? y + ady : y - ady;
                const int rr2 = yy - y0b;
                if (rr2 < 0 || rr2 >= FROWS) continue;   // unstaged: d2>=289
                const int rb = yy * SZ;
                const u32* rw = &win32[rr2 * W32 + 1];
                for (int j = jxs; j <= jxe; ++j) {
                    u32 w = rw[j];
                    if (j == jxs) w &= mlo;
                    if (j == jxe) w &= mhi;
                    while (w) {
                        const int b = __builtin_ctz(w);
                        w &= w - 1;
                        const int xx = (j << 5) + b;
                        const int dxx = xx - x;
                        const u64 d2 = a2 + (u64)(dxx * dxx);
                        ins4_64((d2 << 16) | (u32)(rb + xx), q0, q1, q2, q3);
                    }
                }
            }
        }
        // Cells outside the staged rows have |dy| >= 17 -> d2 >= 289.
        if ((q3 >> 16) < 289ull) {
            ks[0] = q0; ks[1] = q1; ks[2] = q2; ks[3] = q3;
        } else {
            // Tertiary (correctness guarantee; ~never fires): full-image
            // cap-pruned ring ctz scan over the global bitmap, u64 keys.
            const u64 cap2 = q3 >> 16;
            u64 t0 = ~0ull, t1 = ~0ull, t2 = ~0ull, t3 = ~0ull;
            for (int ady = 0; ady < SZ; ++ady) {
                u64 cur = t3 >> 16;
                if (cap2 < cur) cur = cap2;
                const u64 a2 = (u64)(ady * ady);
                if (a2 > cur) break;
                const u64 bound = cur - a2;
                int Rx = (bound >= 65025ull) ? (SZ - 1)
                                             : ((int)sqrtf((float)bound) + 1);
                int xs = x - Rx; if (xs < 0) xs = 0;
                int xe = x + Rx; if (xe > SZ - 1) xe = SZ - 1;
                const int jxs = xs >> 6, jxe = xe >> 6;
                const u64 mlo = (~0ull) << (xs & 63);
                const u64 mhi = (~0ull) >> (63 - (xe & 63));
                for (int s = 0; s < 2; ++s) {
                    if (s && ady == 0) continue;
                    const int yy = s ? y + ady : y - ady;
                    if (yy < 0 || yy > SZ - 1) continue;
                    const int rb = yy * SZ;
                    for (int j = jxs; j <= jxe; ++j) {
                        u64 w = bmc[yy * 4 + j];
                        if (j == jxs) w &= mlo;
                        if (j == jxe) w &= mhi;
                        while (w) {
                            const int b = __builtin_ctzll(w);
                            w &= w - 1;
                            const int xx = (j << 6) + b;
                            const int dxx = xx - x;
                            const u64 d2 = a2 + (u64)(dxx * dxx);
                            ins4_64((d2 << 16) | (u32)(rb + xx),
                                    t0, t1, t2, t3);
                        }
                    }
                }
            }
            ks[0] = t0; ks[1] = t1; ks[2] = t2; ks[3] = t3;
        }
    }

    // Weighted sum in top_k order (ascending (d2, idx)), matching reference.
    float num = 0.0f, den = 0.0f;
    #pragma unroll
    for (int i = 0; i < KNN; ++i) {
        const int idx = (int)(ks[i] & 0xFFFFull);
        const int d2i = (int)(ks[i] >> 16);
        const float dist = sqrtf((float)d2i * (1.0f / 65536.0f));
        num += img[idx] * dist;
        den += dist;
    }
    outc[pix] = num / den;
}

extern "C" void kernel_launch(void* const* d_in, const int* in_sizes, int n_in,
                              void* d_out, int out_size, void* d_ws, size_t ws_size,
                              hipStream_t stream) {
    const float* img = (const float*)d_in[0];   // coded: [1,1,256,256] f32
    const int*   lut = (const int*)d_in[1];     // lookup_table: [256,256] i32
    float*       out = (float*)d_out;           // [1,8,256,256] f32
    u64*         bm  = (u64*)d_ws;              // 64 KB bitmaps

    build_bitmaps<<<dim3(SZ), dim3(256), 0, stream>>>(lut, bm);
    knn_fill<<<dim3(SZ, NUM_CHANNELS), dim3(256), 0, stream>>>(img, bm, out);
}

// Round 2
// 71.566 us; speedup vs baseline: 1.0041x; 1.0030x over previous
//
#include <hip/hip_runtime.h>
#include <math.h>

#define SZ 256
#define KNN 4
#define NUM_CHANNELS 8
#define R 7                  // main window half-width; exact iff 4th d2 < 64
#define WROWS (2 * R + 1)    // 15 main rows (clamped to image)
#define FR 16                // staged row half-range
#define FROWS (2 * FR + 1)   // 33 staged rows; unstaged rows have d2 >= 289
#define W32 10               // LDS row: [1 pad u32][8 data u32][1 pad u32]

typedef unsigned long long u64;
typedef unsigned int u32;

// v_med3_u32: median of three. Used for the branchless sorted-4 insert.
__device__ __forceinline__ u32 med3(u32 a, u32 b, u32 c) {
    u32 r;
    asm("v_med3_u32 %0, %1, %2, %3" : "=v"(r) : "v"(a), "v"(b), "v"(c));
    return r;
}

// Branchless insert into ascending sorted 4 (u32 keys), med3 form:
// 4 VALU (1 min + 3 med3), dependency depth 1 (all read OLD k's).
//   new_k0 = min(key,k0); new_ki = median(key, k_{i-1}, k_i).
// key = (d2 << 16) | flat_idx; main-loop d2 <= 245 -> no overflow.
// Matches jax.lax.top_k ordering incl. lower-index tie-break (keys unique).
// Insert of a SET of unique keys is order-independent -> ring-internal
// processing order is free (exploited by the packed 2-row scan below).
__device__ __forceinline__ void ins4(u32 key, u32& k0, u32& k1,
                                     u32& k2, u32& k3) {
    const u32 n1 = med3(key, k0, k1);
    const u32 n2 = med3(key, k1, k2);
    const u32 n3 = med3(key, k2, k3);
    k0 = (k0 < key) ? k0 : key;
    k1 = n1; k2 = n2; k3 = n3;
}

// u64 variant for fallbacks (d2 up to 130050 would overflow a u32 key).
__device__ __forceinline__ void ins4_64(u64 key, u64& k0, u64& k1,
                                        u64& k2, u64& k3) {
    if (key < k3) {
        u64 m;
        m = (k2 > key) ? k2 : key;  k3 = (k3 < m) ? k3 : m;
        m = (k1 > key) ? k1 : key;  k2 = (k2 < m) ? k2 : m;
        m = (k0 > key) ? k0 : key;  k1 = (k1 < m) ? k1 : m;
        k0 = (k0 < key) ? k0 : key;
    }
}

// 15-bit window extraction: one v_alignbit_b32 over two adjacent u32 words.
// alignbit = (u32)(((u64)hi << 32 | lo) >> (sh & 31)).
__device__ __forceinline__ u32 win15(u32 hi, u32 lo, u32 sh) {
    u32 r;
    asm("v_alignbit_b32 %0, %1, %2, %3" : "=v"(r) : "v"(hi), "v"(lo), "v"(sh));
    return r & 0x7FFFu;
}

// Pass 1: per-channel occupancy bitmaps via wave ballot.
// bm layout: u64[NUM_CHANNELS][SZ][4]; word j covers x in [j*64, j*64+64).
// One ballot pass over lut (256 blocks) is strictly cheaper than per-block
// ballot staging in the fill kernel (R7/R9 both regressed).
__global__ __launch_bounds__(256) void build_bitmaps(
    const int* __restrict__ lut,
    u64* __restrict__ bm)
{
    const int y = blockIdx.x;
    const int x = threadIdx.x;
    const int v = lut[y * SZ + x];
    const int lane = x & 63;
    const int w64 = x >> 6;
    #pragma unroll
    for (int c = 1; c <= NUM_CHANNELS; ++c) {
        u64 bal = __ballot(v == c);
        if (lane == 0) bm[(size_t)(c - 1) * (SZ * 4) + y * 4 + w64] = bal;
    }
}

// Pass 2: stage 33 clamped rows from the global bitmap into LDS (u32 words,
// 1-word pads); wave-uniform |dy|-ring scan with BOTH rows of a ring packed
// into one 31-bit ctz word (halves divergence waste + row overhead); __all
// early break; rare LDS secondary fallback (u64 keys); ~never tertiary.
__global__ __launch_bounds__(256) void knn_fill(
    const float* __restrict__ img,
    const u64*   __restrict__ bm,
    float*       __restrict__ out)
{
    __shared__ u32 win32[FROWS * W32];     // 1320 B padded window bitmap

    const int x   = threadIdx.x;
    const int y   = blockIdx.x;            // block-uniform -> uniform loops
    const int ch  = blockIdx.y;
    const int tid = threadIdx.x;
    const u64* bmc = bm + (size_t)ch * (SZ * 4);

    // Clamped staged-window start (33 full in-image rows).
    int y0b = y - FR;
    if (y0b < 0) y0b = 0;
    if (y0b > SZ - FROWS) y0b = SZ - FROWS;
    // Clamped main-window start (15 full in-image rows).
    int y0m = y - R;
    if (y0m < 0) y0m = 0;
    if (y0m > SZ - WROWS) y0m = SZ - WROWS;
    const int m0 = y0m - y0b;              // main rows offset in staged buf

    // Zero the 66 pad words; load the 132 contiguous u64 bitmap words and
    // scatter each as two u32s (pad indices are 0,9 mod 10 -> disjoint).
    if (tid < FROWS * 2) win32[(tid >> 1) * W32 + (tid & 1) * 9] = 0;
    if (tid < FROWS * 4) {
        const int rr = tid >> 2, j = tid & 3;
        const u64 v = bmc[(y0b + rr) * 4 + j];
        const int b = rr * W32 + 1 + j * 2;
        win32[b]     = (u32)v;
        win32[b + 1] = (u32)(v >> 32);
    }
    __syncthreads();

    const int pix = y * SZ + x;
    float* outc = out + (size_t)ch * (SZ * SZ);

    if ((win32[(y - y0b) * W32 + 1 + (x >> 5)] >> (x & 31)) & 1u) {
        outc[pix] = img[pix];
        return;
    }

    u32 k0 = ~0u, k1 = ~0u, k2 = ~0u, k3 = ~0u;

    // Padded bit position of x-R: 32-bit left pad -> bpos = x - 7 + 32.
    const int bpos = x + (32 - R);
    const int j32  = bpos >> 5;     // 0..8 (word 9 is the right pad)
    const u32 shb  = (u32)(bpos & 31);

    const int mid   = y - y0m;      // main-window row index of y (0..14)
    const int basex = y * SZ + x;   // flat idx of (y, x)

    // Ring scan |dy| = 0..14. Per ring, pack row y-ady (bits 0-14) and row
    // y+ady (bits 16-30) into one word: one ctz loop whose wave trip count
    // is max64(pop_lo + pop_hi) instead of max64(pop_lo) + max64(pop_hi).
    // Ring-internal order differs from the old ±row order, but top-4 insert
    // of unique keys is order-independent -> result bit-identical.
    for (int ady = 0; ady < WROWS; ++ady) {
        const int rlo = mid - ady;
        const int rhi = mid + ady;
        u32 w = 0;
        if (rlo >= 0) {                       // block-uniform branch
            const u32* rw = &win32[(m0 + rlo) * W32 + j32];
            w = win15(rw[1], rw[0], shb);
        }
        if (ady > 0 && rhi < WROWS) {         // block-uniform branch
            const u32* rw = &win32[(m0 + rhi) * W32 + j32];
            w |= win15(rw[1], rw[0], shb) << 16;
        }
        const int dy2  = ady * ady;
        // kb for the lo row; hi row adds step = 2*ady*SZ (r = b>>4).
        const u32 kb   = ((u32)dy2 << 16) + (u32)(basex - (ady << 8));
        const u32 step = (u32)(ady << 9);
        // u32 wraparound exact: candidate flat idx in [0,65535], d2 <= 245.
        while (w) {
            const int b = __builtin_ctz(w);
            w &= w - 1;
            const int dx  = (b & 15) - R;
            const u32 key = kb + (u32)(b >> 4) * step
                               + (((u32)(dx * dx)) << 16) + (u32)dx;
            ins4(key, k0, k1, k2, k3);
        }
        // Remaining rings have |dy| >= ady+1 -> candidate d2 >= (ady+1)^2 >
        // lane's k3_d2 -> key > k3 -> insert is a no-op. Strict '<' keeps
        // tie-break exactness.
        if (__all((k3 >> 16) < (u32)((ady + 1) * (ady + 1)))) break;
    }

    u64 ks[KNN];
    const u32 in_d2 = k3 >> 16;
    // Exactness: any cell outside (15 main rows ∧ |dx|<=7) has d2 >= 64.
    if (in_d2 < (u32)((R + 1) * (R + 1))) {
        ks[0] = k0; ks[1] = k1; ks[2] = k2; ks[3] = k3;  // same bit format
    } else {
        // Secondary fallback (edge pixels, ~1e-3): cap-pruned ring ctz scan
        // over the staged 33-row LDS bitmap (u32 words), u64 keys (d2 up to
        // 66049). cap = in-window 4th-best d2 (0xFFFF if <4 found) — valid
        // upper bound; a2<=cur / Rx+1 conservatism keeps tie-breaks exact.
        const u64 cap = (u64)in_d2;
        u64 q0 = ~0ull, q1 = ~0ull, q2 = ~0ull, q3 = ~0ull;
        for (int ady = 0; ady < FROWS; ++ady) {
            u64 cur = q3 >> 16;
            if (cap < cur) cur = cap;
            const u64 a2 = (u64)(ady * ady);
            if (a2 > cur) break;          // keep a2 == cur (ties)
            const u64 bound = cur - a2;
            int Rx = (bound >= 65025ull) ? (SZ - 1)
                                         : ((int)sqrtf((float)bound) + 1);
            int xs = x - Rx; if (xs < 0) xs = 0;
            int xe = x + Rx; if (xe > SZ - 1) xe = SZ - 1;
            const int jxs = xs >> 5, jxe = xe >> 5;
            const u32 mlo = (~0u) << (xs & 31);
            const u32 mhi = (~0u) >> (31 - (xe & 31));
            #pragma unroll
            for (int s = 0; s < 2; ++s) {
                if (s && ady == 0) continue;
                const int yy = s ? y + ady : y - ady;
                const int rr2 = yy - y0b;
                if (rr2 < 0 || rr2 >= FROWS) continue;   // unstaged: d2>=289
                const int rb = yy * SZ;
                const u32* rw = &win32[rr2 * W32 + 1];
                for (int j = jxs; j <= jxe; ++j) {
                    u32 w = rw[j];
                    if (j == jxs) w &= mlo;
                    if (j == jxe) w &= mhi;
                    while (w) {
                        const int b = __builtin_ctz(w);
                        w &= w - 1;
                        const int xx = (j << 5) + b;
                        const int dxx = xx - x;
                        const u64 d2 = a2 + (u64)(dxx * dxx);
                        ins4_64((d2 << 16) | (u32)(rb + xx), q0, q1, q2, q3);
                    }
                }
            }
        }
        // Cells outside the staged rows have |dy| >= 17 -> d2 >= 289.
        if ((q3 >> 16) < 289ull) {
            ks[0] = q0; ks[1] = q1; ks[2] = q2; ks[3] = q3;
        } else {
            // Tertiary (correctness guarantee; ~never fires): full-image
            // cap-pruned ring ctz scan over the global bitmap, u64 keys.
            const u64 cap2 = q3 >> 16;
            u64 t0 = ~0ull, t1 = ~0ull, t2 = ~0ull, t3 = ~0ull;
            for (int ady = 0; ady < SZ; ++ady) {
                u64 cur = t3 >> 16;
                if (cap2 < cur) cur = cap2;
                const u64 a2 = (u64)(ady * ady);
                if (a2 > cur) break;
                const u64 bound = cur - a2;
                int Rx = (bound >= 65025ull) ? (SZ - 1)
                                             : ((int)sqrtf((float)bound) + 1);
                int xs = x - Rx; if (xs < 0) xs = 0;
                int xe = x + Rx; if (xe > SZ - 1) xe = SZ - 1;
                const int jxs = xs >> 6, jxe = xe >> 6;
                const u64 mlo = (~0ull) << (xs & 63);
                const u64 mhi = (~0ull) >> (63 - (xe & 63));
                for (int s = 0; s < 2; ++s) {
                    if (s && ady == 0) continue;
                    const int yy = s ? y + ady : y - ady;
                    if (yy < 0 || yy > SZ - 1) continue;
                    const int rb = yy * SZ;
                    for (int j = jxs; j <= jxe; ++j) {
                        u64 w = bmc[yy * 4 + j];
                        if (j == jxs) w &= mlo;
                        if (j == jxe) w &= mhi;
                        while (w) {
                            const int b = __builtin_ctzll(w);
                            w &= w - 1;
                            const int xx = (j << 6) + b;
                            const int dxx = xx - x;
                            const u64 d2 = a2 + (u64)(dxx * dxx);
                            ins4_64((d2 << 16) | (u32)(rb + xx),
                                    t0, t1, t2, t3);
                        }
                    }
                }
            }
            ks[0] = t0; ks[1] = t1; ks[2] = t2; ks[3] = t3;
        }
    }

    // Weighted sum in top_k order (ascending (d2, idx)), matching reference.
    float num = 0.0f, den = 0.0f;
    #pragma unroll
    for (int i = 0; i < KNN; ++i) {
        const int idx = (int)(ks[i] & 0xFFFFull);
        const int d2i = (int)(ks[i] >> 16);
        const float dist = sqrtf((float)d2i * (1.0f / 65536.0f));
        num += img[idx] * dist;
        den += dist;
    }
    outc[pix] = num / den;
}

extern "C" void kernel_launch(void* const* d_in, const int* in_sizes, int n_in,
                              void* d_out, int out_size, void* d_ws, size_t ws_size,
                              hipStream_t stream) {
    const float* img = (const float*)d_in[0];   // coded: [1,1,256,256] f32
    const int*   lut = (const int*)d_in[1];     // lookup_table: [256,256] i32
    float*       out = (float*)d_out;           // [1,8,256,256] f32
    u64*         bm  = (u64*)d_ws;              // 64 KB bitmaps

    build_bitmaps<<<dim3(SZ), dim3(256), 0, stream>>>(lut, bm);
    knn_fill<<<dim3(SZ, NUM_CHANNELS), dim3(256), 0, stream>>>(img, bm, out);
}